// Round 20
// baseline (193.962 us; speedup 1.0000x reference)
//
#include <hip/hip_runtime.h>
#include <math.h>

// B=2, S=2048, E=2048, H=16, D=128; qkv width = 2304.
// d_in: 0=hidden(f32) 1=mask(causal, ignored) 2=c_attn_w(f32 E,2304) 3=c_attn_b 4=c_proj_w(f32 E,E) 5=c_proj_b

typedef __attribute__((ext_vector_type(8))) short short8;
typedef __attribute__((ext_vector_type(8))) __bf16 bf16x8;
typedef __attribute__((ext_vector_type(4))) float floatx4;
typedef __attribute__((ext_vector_type(4))) unsigned short ushort4v;
typedef __attribute__((ext_vector_type(2))) unsigned uint2v;
typedef unsigned short ushort;

__device__ __forceinline__ ushort f2bf(float f) {
    unsigned u = __builtin_bit_cast(unsigned, f);
    u += 0x7fffu + ((u >> 16) & 1u);
    return (ushort)(u >> 16);
}
__device__ __forceinline__ unsigned pk2(float a, float b) {
    return (unsigned)f2bf(a) | ((unsigned)f2bf(b) << 16);
}
__device__ __forceinline__ float fexp2(float x) {
#if __has_builtin(__builtin_amdgcn_exp2f)
    return __builtin_amdgcn_exp2f(x);       // v_exp_f32: D = 2^S0
#else
    return exp2f(x);
#endif
}

template <typename V>
__device__ __forceinline__ auto mfma_try(V a, V b, floatx4 c, int)
    -> decltype(__builtin_amdgcn_mfma_f32_16x16x32_bf16(a, b, c, 0, 0, 0)) {
    return __builtin_amdgcn_mfma_f32_16x16x32_bf16(a, b, c, 0, 0, 0);
}
template <typename V>
__device__ __forceinline__ floatx4 mfma_try(V a, V b, floatx4 c, long) {
    return __builtin_amdgcn_mfma_f32_16x16x32_bf16(
        __builtin_bit_cast(bf16x8, a), __builtin_bit_cast(bf16x8, b), c, 0, 0, 0);
}
__device__ __forceinline__ floatx4 mfma_bf16(short8 a, short8 b, floatx4 c) {
    return mfma_try(a, b, c, 0);
}

__device__ __forceinline__ void gld_lds16(const ushort* g, ushort* l) {
    __builtin_amdgcn_global_load_lds(
        (const __attribute__((address_space(1))) unsigned*)(const void*)g,
        (__attribute__((address_space(3))) unsigned*)(void*)l, 16, 0, 0);
}

// ---------------- fused prep: hidden f32->bf16, W1/W2 transpose-convert -----
__global__ __launch_bounds__(256) void prep_all(
    const float* __restrict__ hidden, ushort* __restrict__ hbf,
    const float* __restrict__ W1, ushort* __restrict__ W1T,
    const float* __restrict__ W2, ushort* __restrict__ W2T)
{
    __shared__ ushort T[64][68];
    const int bid = blockIdx.x, tid = threadIdx.x;
    if (bid < 8192) {
        const int i = bid * 256 + tid;
        float4 v = ((const float4*)hidden)[i];
        ushort4v o = {f2bf(v.x), f2bf(v.y), f2bf(v.z), f2bf(v.w)};
        *(ushort4v*)&hbf[(size_t)i * 4] = o;
        return;
    }
    const float* W; ushort* WT; int K, N, n0, k0;
    if (bid < 9344) {
        const int id = bid - 8192;
        W = W1; WT = W1T; K = 2048; N = 2304;
        n0 = (id % 36) * 64; k0 = (id / 36) * 64;
    } else {
        const int id = bid - 9344;
        W = W2; WT = W2T; K = 2048; N = 2048;
        n0 = (id & 31) * 64; k0 = (id >> 5) * 64;
    }
    #pragma unroll
    for (int i = 0; i < 4; ++i) {
        int k = (tid >> 4) + i * 16, n = (tid & 15) * 4;
        float4 v = *(const float4*)&W[(size_t)(k0 + k) * N + n0 + n];
        T[n + 0][k] = f2bf(v.x); T[n + 1][k] = f2bf(v.y);
        T[n + 2][k] = f2bf(v.z); T[n + 3][k] = f2bf(v.w);
    }
    __syncthreads();
    #pragma unroll
    for (int i = 0; i < 4; ++i) {
        int idx = tid + i * 256;
        int n = idx >> 4, c4 = idx & 15;
        *(ushort4v*)&WT[(size_t)(n0 + n) * K + k0 + c4 * 4] =
            *(const ushort4v*)&T[n][c4 * 4];
    }
}

// ---------------- V slice of qkv -> VTg[b][d][s] (bf16 transpose) -----------
__global__ __launch_bounds__(256) void v_transpose(const ushort* __restrict__ qkv,
                                                   ushort* __restrict__ VTg) {
    __shared__ ushort T[64 * 72];                // [d][s] padded
    const int tid = threadIdx.x;
    const int s0 = blockIdx.x * 64, d0 = blockIdx.y * 64, b = blockIdx.z;
    const size_t bS = (size_t)b * 2048;
    #pragma unroll
    for (int i = 0; i < 2; ++i) {
        int idx = tid + i * 256;                 // 0..511
        int s = idx >> 3, d8 = idx & 7;
        short8 v = *(const short8*)&qkv[(bS + s0 + s) * 2304 + 2176 + d0 + d8 * 8];
        #pragma unroll
        for (int j = 0; j < 8; ++j)
            T[(d8 * 8 + j) * 72 + s] = (ushort)v[j];
    }
    __syncthreads();
    #pragma unroll
    for (int i = 0; i < 2; ++i) {
        int idx = tid + i * 256;
        int d = idx >> 3, s8 = idx & 7;
        *(short8*)&VTg[((size_t)b * 128 + d0 + d) * 2048 + s0 + s8 * 8] =
            *(const short8*)&T[d * 72 + s8 * 8];
    }
}

// ---- staging macro for GEMM: one 128x64 tile of A and B into buf_ ----
#define STAGE_AB(k0_, buf_)                                                    \
    {                                                                          \
        _Pragma("unroll")                                                      \
        for (int i_ = 0; i_ < 4; ++i_) {                                       \
            const int c_ = wid * 4 + i_;                                       \
            const int row_ = c_ * 8 + srow;                                    \
            const int lin_ = sphys ^ ((row_ & 7) << 4);                        \
            gld_lds16(&Ag[(size_t)(m0 + row_) * K + (k0_) + (lin_ >> 1)],      \
                      &As[buf_][c_ * 512]);                                    \
            gld_lds16(&Bg[(size_t)(n0 + row_) * K + (k0_) + (lin_ >> 1)],      \
                      &Bs[buf_][c_ * 512]);                                    \
        }                                                                      \
    }

// ---------------- double-buffered GEMM — T3/T4 minimum 2-phase --------------
// Single barrier per K-iteration (guide's m248v2-verified recipe):
//   STAGE(next) -> ds_read(cur)+MFMA -> vmcnt(0) -> s_barrier.
// Hazards: stage targets the buffer whose reads finished before the PREVIOUS
// barrier; vmcnt(0)+barrier makes tile t+1 visible to all waves before use.
// MODE 0: Q pre-scaled by log2(e)/sqrt(128) (base-2 softmax domain, exact).
template <int MODE>
__global__ __launch_bounds__(256, 2) void gemm_db(
    const ushort* __restrict__ Ag, const ushort* __restrict__ Bg,
    const float* __restrict__ bias, void* __restrict__ C, int M, int N, int K)
{
    __shared__ ushort As[2][8192];
    __shared__ ushort Bs[2][8192];
    const int tid = threadIdx.x, lane = tid & 63, wid = tid >> 6;
    const int wr = wid >> 1, wc = wid & 1;
    const int lg = lane >> 4, li = lane & 15;
    const int srow = lane >> 3;
    const int sphys = (lane & 7) * 16;

    // T1: XCD swizzle (nwg % 8 == 0 for both launches)
    const int nbx = gridDim.x;
    const int nwg = nbx * gridDim.y;
    const int bid = blockIdx.y * nbx + blockIdx.x;
    const int swz = (bid & 7) * (nwg >> 3) + (bid >> 3);
    const int m0 = (swz / nbx) * 128, n0 = (swz % nbx) * 128;

    floatx4 acc[4][4] = {};
    const int niter = K >> 6;

    STAGE_AB(0, 0);                              // prologue
    asm volatile("s_waitcnt vmcnt(0)" ::: "memory");
    __builtin_amdgcn_s_barrier();                // tile 0 visible to all waves

    for (int it = 0; it < niter; ++it) {
        if (it + 1 < niter)
            STAGE_AB((it + 1) * 64, (it + 1) & 1);   // issue next tile first

        const ushort* Ab = As[it & 1];
        __builtin_amdgcn_s_setprio(1);
        #pragma unroll
        for (int kk = 0; kk < 2; ++kk) {
            short8 af[4], bfv[4];
            const int pb = (kk * 64 + lg * 16) ^ ((li & 7) << 4);
            #pragma unroll
            for (int m = 0; m < 4; ++m)
                af[m] = *(const short8*)&Ab[(wr * 64 + m * 16 + li) * 64 + (pb >> 1)];
            #pragma unroll
            for (int n = 0; n < 4; ++n)
                bfv[n] = *(const short8*)&Bs[it & 1][(wc * 64 + n * 16 + li) * 64 + (pb >> 1)];
            #pragma unroll
            for (int m = 0; m < 4; ++m)
                #pragma unroll
                for (int n = 0; n < 4; ++n)
                    acc[m][n] = mfma_bf16(af[m], bfv[n], acc[m][n]);
        }
        __builtin_amdgcn_s_setprio(0);

        asm volatile("s_waitcnt vmcnt(0)" ::: "memory");  // next tile landed
        __builtin_amdgcn_s_barrier();            // ONE barrier per iteration
    }

    #pragma unroll
    for (int m = 0; m < 4; ++m) {
        #pragma unroll
        for (int n = 0; n < 4; ++n) {
            const int col = n0 + wc * 64 + n * 16 + li;
            const float bv = bias[col];
            #pragma unroll
            for (int r = 0; r < 4; ++r) {
                const int row = m0 + wr * 64 + m * 16 + lg * 4 + r;
                float v = acc[m][n][r] + bv;
                if constexpr (MODE == 0) {
                    if (col < 2048) v *= 0.12751744559917524f;  // log2(e)/sqrt(128)
                    ((ushort*)C)[(size_t)row * N + col] = f2bf(v);
                } else {
                    ((float*)C)[(size_t)row * N + col] = v;
                }
            }
        }
    }
}

// stage macro (group-local): 256 threads of one wave-group stage one 64-key tile
#define STAGE_KV(t_, Kdst, Vdst)                                               \
    {                                                                          \
        const int k0_ = (t_) * 64;                                             \
        _Pragma("unroll")                                                      \
        for (int i_ = 0; i_ < 4; ++i_) {                                       \
            const int idx_ = gtid + i_ * 256;                                  \
            const int row_ = idx_ >> 4, g_ = idx_ & 15;                        \
            const int src_ = (g_ * 16) ^ ((row_ & 7) << 4);                    \
            gld_lds16(&qkv[(bS + k0_ + row_) * QKV + E + (src_ >> 1)],         \
                      &(Kdst)[(i_ * 256 + gwid * 64) * 8]);                    \
        }                                                                      \
        _Pragma("unroll")                                                      \
        for (int i_ = 0; i_ < 4; ++i_) {                                       \
            const int idx_ = gtid + i_ * 256;                                  \
            const int d_ = idx_ >> 3, kg_ = idx_ & 7;                          \
            gld_lds16(&VTg[((size_t)b * 128 + d_) * 2048 + k0_ +               \
                           ((kg_ ^ (d_ & 7)) << 3)],                           \
                      &(Vdst)[(i_ * 256 + gwid * 64) * 8]);                    \
        }                                                                      \
    }

// ---------------- MQA flash attention (r19 math; single-barrier K-loop) -----
// UNCONDITIONAL dataflow (r9/r18 lesson). Masking by value (-2e30).
// Base-2 softmax domain (Q pre-scaled by log2e/sqrt(128)).
__global__ __launch_bounds__(512, 2) void attn_kernel(
    const ushort* __restrict__ qkv,   // [B*S][2304] bf16; Q pre-scaled (log2 dom.)
    const ushort* __restrict__ VTg,   // [B][128][2048] bf16 (V transposed)
    ushort* __restrict__ out)         // [B*S][2048] bf16
{
    constexpr int S = 2048, Dh = 128, QKV = 2304, E = 2048;
    __shared__ ushort lds[81920];               // 160.0 KB (full pool, 1 block/CU)
    ushort* Ps = lds + 65536;

    const int tid = threadIdx.x, lane = tid & 63, wid = tid >> 6;
    const int gtid = tid & 255;                  // thread within wave-group
    const int grp = wid >> 2, gwid = wid & 3;    // group 0/1, wave within group
    const int lg = lane >> 4, li = lane & 15;
    const int pr = blockIdx.x;                   // 0..7: pair (pr, 15-pr)
    const int h = blockIdx.y, b = blockIdx.z;
    const size_t bS = (size_t)b * S;

    for (int pass = 0; pass < 2; ++pass) {
        const int st = pass ? (15 - pr) : pr;
        const int qA = st * 128 + gwid * 16;     // set A = q-tile 2st
        const int qB = qA + 64;                  // set B = q-tile 2st+1
        const int niter = st + 1;                // tiles per group
        const int tbase = grp * niter;           // group 0: [0,st+1), group 1: [st+1,2st+2)

        short8 qfA[4], qfB[4];
        #pragma unroll
        for (int dc = 0; dc < 4; ++dc) {
            qfA[dc] = *(const short8*)&qkv[(bS + qA + li) * QKV + h * Dh + dc * 32 + lg * 8];
            qfB[dc] = *(const short8*)&qkv[(bS + qB + li) * QKV + h * Dh + dc * 32 + lg * 8];
        }

        floatx4 oA[8] = {}, oB[8] = {};
        float mA = -1e30f, lA = 0.f, mB = -1e30f, lB = 0.f;

        STAGE_KV(tbase, lds + (grp * 2) * 8192, lds + 32768 + (grp * 2) * 8192);
        asm volatile("s_waitcnt vmcnt(0)" ::: "memory");
        __builtin_amdgcn_s_barrier();            // tile tbase visible

        for (int it = 0; it < niter; ++it) {
            const int t = tbase + it;
            ushort* Kcur = lds + (grp * 2 + (it & 1)) * 8192;
            ushort* Vcur = lds + 32768 + (grp * 2 + (it & 1)) * 8192;
            if (it + 1 < niter) {
                STAGE_KV(t + 1, lds + (grp * 2 + ((it + 1) & 1)) * 8192,
                         lds + 32768 + (grp * 2 + ((it + 1) & 1)) * 8192);
            }

            floatx4 sA[4] = {{0,0,0,0},{0,0,0,0},{0,0,0,0},{0,0,0,0}};
            floatx4 sB[4] = {{0,0,0,0},{0,0,0,0},{0,0,0,0},{0,0,0,0}};
            __builtin_amdgcn_s_setprio(1);
            #pragma unroll
            for (int dc = 0; dc < 4; ++dc) {
                #pragma unroll
                for (int kb = 0; kb < 4; ++kb) {
                    short8 kf = *(const short8*)&Kcur[(kb * 16 + li) * 128 +
                                                      (((dc * 4 + lg) ^ (li & 7)) << 3)];
                    sA[kb] = mfma_bf16(kf, qfA[dc], sA[kb]);
                    sB[kb] = mfma_bf16(kf, qfB[dc], sB[kb]);
                }
            }
            __builtin_amdgcn_s_setprio(0);

            if (t == 2 * st) {                   // diagonal tile for set A
                #pragma unroll
                for (int kb = 0; kb < 4; ++kb)
                    #pragma unroll
                    for (int r = 0; r < 4; ++r)
                        if (kb * 16 + lg * 4 + r > gwid * 16 + li) sA[kb][r] = -2e30f;
            }
            if (t == 2 * st + 1) {               // last tile: A fully masked, B diagonal
                #pragma unroll
                for (int kb = 0; kb < 4; ++kb)
                    #pragma unroll
                    for (int r = 0; r < 4; ++r) {
                        sA[kb][r] = -2e30f;
                        if (kb * 16 + lg * 4 + r > gwid * 16 + li) sB[kb][r] = -2e30f;
                    }
            }

            { // softmax set A (defer-rescale, exact; base-2 domain)
                float mt = fmaxf(fmaxf(fmaxf(sA[0][0], sA[0][1]), fmaxf(sA[0][2], sA[0][3])),
                                 fmaxf(fmaxf(sA[1][0], sA[1][1]), fmaxf(sA[1][2], sA[1][3])));
                mt = fmaxf(mt, fmaxf(fmaxf(fmaxf(sA[2][0], sA[2][1]), fmaxf(sA[2][2], sA[2][3])),
                                     fmaxf(fmaxf(sA[3][0], sA[3][1]), fmaxf(sA[3][2], sA[3][3]))));
                mt = fmaxf(mt, __shfl_xor(mt, 16));
                mt = fmaxf(mt, __shfl_xor(mt, 32));
                if (!__all(mt <= mA)) {
                    const float mn = fmaxf(mA, mt);
                    const float sc = fexp2(mA - mn);
                    mA = mn;
                    lA *= sc;
                    #pragma unroll
                    for (int db = 0; db < 8; ++db) oA[db] *= sc;
                }
                float rs = 0.f;
                #pragma unroll
                for (int kb = 0; kb < 4; ++kb)
                    #pragma unroll
                    for (int r = 0; r < 4; ++r) {
                        float p = fexp2(sA[kb][r] - mA);
                        sA[kb][r] = p; rs += p;
                    }
                rs += __shfl_xor(rs, 16);
                rs += __shfl_xor(rs, 32);
                lA += rs;
                #pragma unroll
                for (int kb = 0; kb < 4; ++kb) {
                    const int g = kb * 2 + (lg >> 1);
                    const int sw = ((g ^ (li & 7)) << 3) + ((lg & 1) * 4);
                    uint2v w = {pk2(sA[kb][0], sA[kb][1]), pk2(sA[kb][2], sA[kb][3])};
                    *(uint2v*)&Ps[wid * 2048 + li * 64 + sw] = w;
                }
            }
            { // softmax set B (defer-rescale, exact; base-2 domain)
                float mt = fmaxf(fmaxf(fmaxf(sB[0][0], sB[0][1]), fmaxf(sB[0][2], sB[0][3])),
                                 fmaxf(fmaxf(sB[1][0], sB[1][1]), fmaxf(sB[1][2], sB[1][3])));
                mt = fmaxf(mt, fmaxf(fmaxf(fmaxf(sB[2][0], sB[2][1]), fmaxf(sB[2][2], sB[2][3])),
                                     fmaxf(fmaxf(sB[3][0], sB[3][1]), fmaxf(sB[3][2], sB[3][3]))));
                mt = fmaxf(mt, __shfl_xor(mt, 16));
                mt = fmaxf(mt, __shfl_xor(mt, 32));
                if (!__all(mt <= mB)) {
                    const float mn = fmaxf(mB, mt);
                    const float sc = fexp2(mB - mn);
                    mB = mn;
                    lB *= sc;
                    #pragma unroll
                    for (int db = 0; db < 8; ++db) oB[db] *= sc;
                }
                float rs = 0.f;
                #pragma unroll
                for (int kb = 0; kb < 4; ++kb)
                    #pragma unroll
                    for (int r = 0; r < 4; ++r) {
                        float p = fexp2(sB[kb][r] - mB);
                        sB[kb][r] = p; rs += p;
                    }
                rs += __shfl_xor(rs, 16);
                rs += __shfl_xor(rs, 32);
                lB += rs;
                #pragma unroll
                for (int kb = 0; kb < 4; ++kb) {
                    const int g = kb * 2 + (lg >> 1);
                    const int sw = ((g ^ (li & 7)) << 3) + ((lg & 1) * 4);
                    uint2v w = {pk2(sB[kb][0], sB[kb][1]), pk2(sB[kb][2], sB[kb][3])};
                    *(uint2v*)&Ps[wid * 2048 + 1024 + li * 64 + sw] = w;
                }
            }

            __builtin_amdgcn_s_setprio(1);
            #pragma unroll
            for (int kc = 0; kc < 2; ++kc) {
                short8 pA = *(const short8*)&Ps[wid * 2048 + li * 64 +
                                                (((kc * 4 + lg) ^ (li & 7)) << 3)];
                short8 pB = *(const short8*)&Ps[wid * 2048 + 1024 + li * 64 +
                                                (((kc * 4 + lg) ^ (li & 7)) << 3)];
                #pragma unroll
                for (int db = 0; db < 8; ++db) {
                    short8 vt = *(const short8*)&Vcur[(db * 16 + li) * 64 +
                                                      (((kc * 4 + lg) ^ (li & 7)) << 3)];
                    oA[db] = mfma_bf16(vt, pA, oA[db]);
                    oB[db] = mfma_bf16(vt, pB, oB[db]);
                }
            }
            __builtin_amdgcn_s_setprio(0);

            asm volatile("s_waitcnt vmcnt(0)" ::: "memory");  // next tile landed
            __builtin_amdgcn_s_barrier();        // ONE barrier per iteration
        }

        // ---- cross-group merge + store (per set; fbuf [4][64][36] floats) ----
        float* fbuf = (float*)lds;
        ushort* Pw = lds + wid * 2176;           // wid 0..3 only (grp 0)
        __syncthreads();

        // ===== SET A =====
        if (grp == 1) {
            float* dst = fbuf + (gwid * 64 + lane) * 36;
            #pragma unroll
            for (int db = 0; db < 8; ++db) *(floatx4*)&dst[db * 4] = oA[db];
            dst[32] = mA; dst[33] = lA;
        }
        __syncthreads();
        if (grp == 0) {
            const float* src = fbuf + (gwid * 64 + lane) * 36;
            const float m1 = src[32], l1 = src[33];
            const float mm = fmaxf(mA, m1);
            const float s0 = fexp2(mA - mm), s1 = fexp2(m1 - mm);
            #pragma unroll
            for (int db = 0; db < 8; ++db) {
                floatx4 o1 = *(const floatx4*)&src[db * 4];
                oA[db] = oA[db] * s0 + o1 * s1;
            }
            lA = lA * s0 + l1 * s1;
        }
        __syncthreads();
        if (grp == 0) {
            const float inv = 1.0f / lA;
            #pragma unroll
            for (int db = 0; db < 8; ++db) {
                *(unsigned*)&Pw[li * 136 + db * 16 + lg * 4]     = pk2(oA[db][0] * inv, oA[db][1] * inv);
                *(unsigned*)&Pw[li * 136 + db * 16 + lg * 4 + 2] = pk2(oA[db][2] * inv, oA[db][3] * inv);
            }
            #pragma unroll
            for (int i = 0; i < 4; ++i) {
                const int q = lane >> 2, d8 = (lane & 3) + i * 4;
                short8 vv = *(const short8*)&Pw[q * 136 + d8 * 8];
                *(short8*)&out[(bS + qA + q) * E + h * Dh + d8 * 8] = vv;
            }
        }
        __syncthreads();

        // ===== SET B =====
        if (grp == 1) {
            float* dst = fbuf + (gwid * 64 + lane) * 36;
            #pragma unroll
            for (int db = 0; db < 8; ++db) *(floatx4*)&dst[db * 4] = oB[db];
            dst[32] = mB; dst[33] = lB;
        }
        __syncthreads();
        if (grp == 0) {
            const float* src = fbuf + (gwid * 64 + lane) * 36;
            const float m1 = src[32], l1 = src[33];
            const float mm = fmaxf(mB, m1);
            const float s0 = fexp2(mB - mm), s1 = fexp2(m1 - mm);
            #pragma unroll
            for (int db = 0; db < 8; ++db) {
                floatx4 o1 = *(const floatx4*)&src[db * 4];
                oB[db] = oB[db] * s0 + o1 * s1;
            }
            lB = lB * s0 + l1 * s1;
        }
        __syncthreads();
        if (grp == 0) {
            const float inv = 1.0f / lB;
            #pragma unroll
            for (int db = 0; db < 8; ++db) {
                *(unsigned*)&Pw[li * 136 + db * 16 + lg * 4]     = pk2(oB[db][0] * inv, oB[db][1] * inv);
                *(unsigned*)&Pw[li * 136 + db * 16 + lg * 4 + 2] = pk2(oB[db][2] * inv, oB[db][3] * inv);
            }
            #pragma unroll
            for (int i = 0; i < 4; ++i) {
                const int q = lane >> 2, d8 = (lane & 3) + i * 4;
                short8 vv = *(const short8*)&Pw[q * 136 + d8 * 8];
                *(short8*)&out[(bS + qB + q) * E + h * Dh + d8 * 8] = vv;
            }
        }
        __syncthreads();
    }
}

extern "C" void kernel_launch(void* const* d_in, const int* in_sizes, int n_in,
                              void* d_out, int out_size, void* d_ws, size_t ws_size,
                              hipStream_t stream) {
    (void)in_sizes; (void)n_in; (void)out_size; (void)ws_size;
    const float* hidden   = (const float*)d_in[0];
    const float* c_attn_w = (const float*)d_in[2];
    const float* c_attn_b = (const float*)d_in[3];
    const float* c_proj_w = (const float*)d_in[4];
    const float* c_proj_b = (const float*)d_in[5];
    float* outp = (float*)d_out;

    char* ws = (char*)d_ws;
    ushort* hbf  = (ushort*)ws;                                    // 4096x2048 bf16 -> later attn buf
    ushort* W1T  = (ushort*)(ws + (size_t)16777216);               // 2304x2048 bf16
    ushort* W2T  = (ushort*)(ws + (size_t)16777216 + 9437184);     // 2048x2048 bf16
    ushort* qkv  = (ushort*)(ws + (size_t)16777216 + 9437184 + 8388608);  // 4096x2304 bf16
    ushort* VTg  = (ushort*)(ws + (size_t)16777216 + 9437184 + 8388608 + 18874368); // 2x128x2048
    ushort* attn = hbf;   // reuse: hidden_bf16 dead after GEMM1

    prep_all<<<10368, 256, 0, stream>>>(hidden, hbf, c_attn_w, W1T, c_proj_w, W2T);

    gemm_db<0><<<dim3(18, 32), 256, 0, stream>>>(hbf, W1T, c_attn_b, qkv, 4096, 2304, 2048);
    v_transpose<<<dim3(32, 2, 2), 256, 0, stream>>>(qkv, VTg);
    attn_kernel<<<dim3(8, 16, 2), 512, 0, stream>>>(qkv, VTg, attn);
    gemm_db<1><<<dim3(16, 32), 256, 0, stream>>>(attn, W2T, c_proj_b, outp, 4096, 2048, 2048);
}

// Round 21
// 192.282 us; speedup vs baseline: 1.0087x; 1.0087x over previous
//
#include <hip/hip_runtime.h>
#include <math.h>

// B=2, S=2048, E=2048, H=16, D=128; qkv width = 2304.
// d_in: 0=hidden(f32) 1=mask(causal, ignored) 2=c_attn_w(f32 E,2304) 3=c_attn_b 4=c_proj_w(f32 E,E) 5=c_proj_b

typedef __attribute__((ext_vector_type(8))) short short8;
typedef __attribute__((ext_vector_type(8))) __bf16 bf16x8;
typedef __attribute__((ext_vector_type(4))) float floatx4;
typedef __attribute__((ext_vector_type(4))) unsigned short ushort4v;
typedef __attribute__((ext_vector_type(2))) unsigned uint2v;
typedef unsigned short ushort;

__device__ __forceinline__ ushort f2bf(float f) {
    unsigned u = __builtin_bit_cast(unsigned, f);
    u += 0x7fffu + ((u >> 16) & 1u);
    return (ushort)(u >> 16);
}
__device__ __forceinline__ unsigned pk2(float a, float b) {
    return (unsigned)f2bf(a) | ((unsigned)f2bf(b) << 16);
}
__device__ __forceinline__ float fexp2(float x) {
#if __has_builtin(__builtin_amdgcn_exp2f)
    return __builtin_amdgcn_exp2f(x);       // v_exp_f32: D = 2^S0
#else
    return exp2f(x);
#endif
}

template <typename V>
__device__ __forceinline__ auto mfma_try(V a, V b, floatx4 c, int)
    -> decltype(__builtin_amdgcn_mfma_f32_16x16x32_bf16(a, b, c, 0, 0, 0)) {
    return __builtin_amdgcn_mfma_f32_16x16x32_bf16(a, b, c, 0, 0, 0);
}
template <typename V>
__device__ __forceinline__ floatx4 mfma_try(V a, V b, floatx4 c, long) {
    return __builtin_amdgcn_mfma_f32_16x16x32_bf16(
        __builtin_bit_cast(bf16x8, a), __builtin_bit_cast(bf16x8, b), c, 0, 0, 0);
}
__device__ __forceinline__ floatx4 mfma_bf16(short8 a, short8 b, floatx4 c) {
    return mfma_try(a, b, c, 0);
}

__device__ __forceinline__ void gld_lds16(const ushort* g, ushort* l) {
    __builtin_amdgcn_global_load_lds(
        (const __attribute__((address_space(1))) unsigned*)(const void*)g,
        (__attribute__((address_space(3))) unsigned*)(void*)l, 16, 0, 0);
}

// ---------------- fused prep: hidden f32->bf16, W1/W2 transpose-convert -----
__global__ __launch_bounds__(256) void prep_all(
    const float* __restrict__ hidden, ushort* __restrict__ hbf,
    const float* __restrict__ W1, ushort* __restrict__ W1T,
    const float* __restrict__ W2, ushort* __restrict__ W2T)
{
    __shared__ ushort T[64][68];
    const int bid = blockIdx.x, tid = threadIdx.x;
    if (bid < 8192) {
        const int i = bid * 256 + tid;
        float4 v = ((const float4*)hidden)[i];
        ushort4v o = {f2bf(v.x), f2bf(v.y), f2bf(v.z), f2bf(v.w)};
        *(ushort4v*)&hbf[(size_t)i * 4] = o;
        return;
    }
    const float* W; ushort* WT; int K, N, n0, k0;
    if (bid < 9344) {
        const int id = bid - 8192;
        W = W1; WT = W1T; K = 2048; N = 2304;
        n0 = (id % 36) * 64; k0 = (id / 36) * 64;
    } else {
        const int id = bid - 9344;
        W = W2; WT = W2T; K = 2048; N = 2048;
        n0 = (id & 31) * 64; k0 = (id >> 5) * 64;
    }
    #pragma unroll
    for (int i = 0; i < 4; ++i) {
        int k = (tid >> 4) + i * 16, n = (tid & 15) * 4;
        float4 v = *(const float4*)&W[(size_t)(k0 + k) * N + n0 + n];
        T[n + 0][k] = f2bf(v.x); T[n + 1][k] = f2bf(v.y);
        T[n + 2][k] = f2bf(v.z); T[n + 3][k] = f2bf(v.w);
    }
    __syncthreads();
    #pragma unroll
    for (int i = 0; i < 4; ++i) {
        int idx = tid + i * 256;
        int n = idx >> 4, c4 = idx & 15;
        *(ushort4v*)&WT[(size_t)(n0 + n) * K + k0 + c4 * 4] =
            *(const ushort4v*)&T[n][c4 * 4];
    }
}

// ---------------- V slice of qkv -> VTg[b][d][s] (bf16 transpose) -----------
__global__ __launch_bounds__(256) void v_transpose(const ushort* __restrict__ qkv,
                                                   ushort* __restrict__ VTg) {
    __shared__ ushort T[64 * 72];                // [d][s] padded
    const int tid = threadIdx.x;
    const int s0 = blockIdx.x * 64, d0 = blockIdx.y * 64, b = blockIdx.z;
    const size_t bS = (size_t)b * 2048;
    #pragma unroll
    for (int i = 0; i < 2; ++i) {
        int idx = tid + i * 256;                 // 0..511
        int s = idx >> 3, d8 = idx & 7;
        short8 v = *(const short8*)&qkv[(bS + s0 + s) * 2304 + 2176 + d0 + d8 * 8];
        #pragma unroll
        for (int j = 0; j < 8; ++j)
            T[(d8 * 8 + j) * 72 + s] = (ushort)v[j];
    }
    __syncthreads();
    #pragma unroll
    for (int i = 0; i < 2; ++i) {
        int idx = tid + i * 256;
        int d = idx >> 3, s8 = idx & 7;
        *(short8*)&VTg[((size_t)b * 128 + d0 + d) * 2048 + s0 + s8 * 8] =
            *(const short8*)&T[d * 72 + s8 * 8];
    }
}

// ---- staging macro for GEMM: one 128x64 tile of A and B into buf_ ----
#define STAGE_AB(k0_, buf_)                                                    \
    {                                                                          \
        _Pragma("unroll")                                                      \
        for (int i_ = 0; i_ < 4; ++i_) {                                       \
            const int c_ = wid * 4 + i_;                                       \
            const int row_ = c_ * 8 + srow;                                    \
            const int lin_ = sphys ^ ((row_ & 7) << 4);                        \
            gld_lds16(&Ag[(size_t)(m0 + row_) * K + (k0_) + (lin_ >> 1)],      \
                      &As[buf_][c_ * 512]);                                    \
            gld_lds16(&Bg[(size_t)(n0 + row_) * K + (k0_) + (lin_ >> 1)],      \
                      &Bs[buf_][c_ * 512]);                                    \
        }                                                                      \
    }

// ---------------- double-buffered GEMM (r14/r16-verified) -------------------
// MODE 0: Q columns pre-scaled by log2(e)/sqrt(128) -> attn softmax runs in
// base-2 domain (exact: 2^(s*log2e) = e^s).
template <int MODE>
__global__ __launch_bounds__(256, 2) void gemm_db(
    const ushort* __restrict__ Ag, const ushort* __restrict__ Bg,
    const float* __restrict__ bias, void* __restrict__ C, int M, int N, int K)
{
    __shared__ ushort As[2][8192];
    __shared__ ushort Bs[2][8192];
    const int tid = threadIdx.x, lane = tid & 63, wid = tid >> 6;
    const int wr = wid >> 1, wc = wid & 1;
    const int lg = lane >> 4, li = lane & 15;
    const int srow = lane >> 3;
    const int sphys = (lane & 7) * 16;

    // T1: XCD swizzle (nwg % 8 == 0 for both launches)
    const int nbx = gridDim.x;
    const int nwg = nbx * gridDim.y;
    const int bid = blockIdx.y * nbx + blockIdx.x;
    const int swz = (bid & 7) * (nwg >> 3) + (bid >> 3);
    const int m0 = (swz / nbx) * 128, n0 = (swz % nbx) * 128;

    floatx4 acc[4][4] = {};
    const int niter = K >> 6;

    STAGE_AB(0, 0);                              // prologue: tile 0 in flight

    for (int it = 0; it < niter; ++it) {
        __builtin_amdgcn_s_barrier();            // [A] all waves done compute(it-1); NO drain
        if (it + 1 < niter) {
            STAGE_AB((it + 1) * 64, (it + 1) & 1);   // issue next tile (stays in flight)
            asm volatile("s_waitcnt vmcnt(8)" ::: "memory");  // my tile-it granules landed
        } else {
            asm volatile("s_waitcnt vmcnt(0)" ::: "memory");
        }
        __builtin_amdgcn_sched_barrier(0);
        __builtin_amdgcn_s_barrier();            // [D] everyone's tile staged; next flying
        __builtin_amdgcn_sched_barrier(0);

        const ushort* Ab = As[it & 1];
        __builtin_amdgcn_s_setprio(1);
        #pragma unroll
        for (int kk = 0; kk < 2; ++kk) {
            short8 af[4], bfv[4];
            const int pb = (kk * 64 + lg * 16) ^ ((li & 7) << 4);
            #pragma unroll
            for (int m = 0; m < 4; ++m)
                af[m] = *(const short8*)&Ab[(wr * 64 + m * 16 + li) * 64 + (pb >> 1)];
            #pragma unroll
            for (int n = 0; n < 4; ++n)
                bfv[n] = *(const short8*)&Bs[it & 1][(wc * 64 + n * 16 + li) * 64 + (pb >> 1)];
            #pragma unroll
            for (int m = 0; m < 4; ++m)
                #pragma unroll
                for (int n = 0; n < 4; ++n)
                    acc[m][n] = mfma_bf16(af[m], bfv[n], acc[m][n]);
        }
        __builtin_amdgcn_s_setprio(0);
    }

    #pragma unroll
    for (int m = 0; m < 4; ++m) {
        #pragma unroll
        for (int n = 0; n < 4; ++n) {
            const int col = n0 + wc * 64 + n * 16 + li;
            const float bv = bias[col];
            #pragma unroll
            for (int r = 0; r < 4; ++r) {
                const int row = m0 + wr * 64 + m * 16 + lg * 4 + r;
                float v = acc[m][n][r] + bv;
                if constexpr (MODE == 0) {
                    if (col < 2048) v *= 0.12751744559917524f;  // log2(e)/sqrt(128)
                    ((ushort*)C)[(size_t)row * N + col] = f2bf(v);
                } else {
                    ((float*)C)[(size_t)row * N + col] = v;
                }
            }
        }
    }
}

// stage macro (group-local): 256 threads of one wave-group stage one 64-key tile
#define STAGE_KV(t_, Kdst, Vdst)                                               \
    {                                                                          \
        const int k0_ = (t_) * 64;                                             \
        _Pragma("unroll")                                                      \
        for (int i_ = 0; i_ < 4; ++i_) {                                       \
            const int idx_ = gtid + i_ * 256;                                  \
            const int row_ = idx_ >> 4, g_ = idx_ & 15;                        \
            const int src_ = (g_ * 16) ^ ((row_ & 7) << 4);                    \
            gld_lds16(&qkv[(bS + k0_ + row_) * QKV + E + (src_ >> 1)],         \
                      &(Kdst)[(i_ * 256 + gwid * 64) * 8]);                    \
        }                                                                      \
        _Pragma("unroll")                                                      \
        for (int i_ = 0; i_ < 4; ++i_) {                                       \
            const int idx_ = gtid + i_ * 256;                                  \
            const int d_ = idx_ >> 3, kg_ = idx_ & 7;                          \
            gld_lds16(&VTg[((size_t)b * 128 + d_) * 2048 + k0_ +               \
                           ((kg_ ^ (d_ & 7)) << 3)],                           \
                      &(Vdst)[(i_ * 256 + gwid * 64) * 8]);                    \
        }                                                                      \
    }

// ---------------- MQA flash attention (r16 structure; base-2 softmax) -------
// UNCONDITIONAL dataflow (r9/r18 lesson: any control-flow guard on the
// register arrays demotes them to scratch). Masking is by value (-2e30).
__global__ __launch_bounds__(512, 2) void attn_kernel(
    const ushort* __restrict__ qkv,   // [B*S][2304] bf16; Q pre-scaled (log2 dom.)
    const ushort* __restrict__ VTg,   // [B][128][2048] bf16 (V transposed)
    ushort* __restrict__ out)         // [B*S][2048] bf16
{
    constexpr int S = 2048, Dh = 128, QKV = 2304, E = 2048;
    __shared__ ushort lds[81920];               // 160.0 KB (full pool, 1 block/CU)
    ushort* Ps = lds + 65536;

    const int tid = threadIdx.x, lane = tid & 63, wid = tid >> 6;
    const int gtid = tid & 255;                  // thread within wave-group
    const int grp = wid >> 2, gwid = wid & 3;    // group 0/1, wave within group
    const int lg = lane >> 4, li = lane & 15;
    const int pr = blockIdx.x;                   // 0..7: pair (pr, 15-pr)
    const int h = blockIdx.y, b = blockIdx.z;
    const size_t bS = (size_t)b * S;

    for (int pass = 0; pass < 2; ++pass) {
        const int st = pass ? (15 - pr) : pr;
        const int qA = st * 128 + gwid * 16;     // set A = q-tile 2st
        const int qB = qA + 64;                  // set B = q-tile 2st+1
        const int niter = st + 1;                // tiles per group
        const int tbase = grp * niter;           // group 0: [0,st+1), group 1: [st+1,2st+2)

        short8 qfA[4], qfB[4];
        #pragma unroll
        for (int dc = 0; dc < 4; ++dc) {
            qfA[dc] = *(const short8*)&qkv[(bS + qA + li) * QKV + h * Dh + dc * 32 + lg * 8];
            qfB[dc] = *(const short8*)&qkv[(bS + qB + li) * QKV + h * Dh + dc * 32 + lg * 8];
        }

        floatx4 oA[8] = {}, oB[8] = {};
        float mA = -1e30f, lA = 0.f, mB = -1e30f, lB = 0.f;

        STAGE_KV(tbase, lds + (grp * 2) * 8192, lds + 32768 + (grp * 2) * 8192);

        for (int it = 0; it < niter; ++it) {
            const int t = tbase + it;
            __builtin_amdgcn_s_barrier();        // [A]
            ushort* Kcur = lds + (grp * 2 + (it & 1)) * 8192;
            ushort* Vcur = lds + 32768 + (grp * 2 + (it & 1)) * 8192;
            if (it + 1 < niter) {
                STAGE_KV(t + 1, lds + (grp * 2 + ((it + 1) & 1)) * 8192,
                         lds + 32768 + (grp * 2 + ((it + 1) & 1)) * 8192);
                asm volatile("s_waitcnt vmcnt(8)" ::: "memory");
            } else {
                asm volatile("s_waitcnt vmcnt(0)" ::: "memory");
            }
            __builtin_amdgcn_sched_barrier(0);
            __builtin_amdgcn_s_barrier();        // [D]

            floatx4 sA[4] = {{0,0,0,0},{0,0,0,0},{0,0,0,0},{0,0,0,0}};
            floatx4 sB[4] = {{0,0,0,0},{0,0,0,0},{0,0,0,0},{0,0,0,0}};
            __builtin_amdgcn_s_setprio(1);
            #pragma unroll
            for (int dc = 0; dc < 4; ++dc) {
                #pragma unroll
                for (int kb = 0; kb < 4; ++kb) {
                    short8 kf = *(const short8*)&Kcur[(kb * 16 + li) * 128 +
                                                      (((dc * 4 + lg) ^ (li & 7)) << 3)];
                    sA[kb] = mfma_bf16(kf, qfA[dc], sA[kb]);
                    sB[kb] = mfma_bf16(kf, qfB[dc], sB[kb]);
                }
            }
            __builtin_amdgcn_s_setprio(0);

            if (t == 2 * st) {                   // diagonal tile for set A
                #pragma unroll
                for (int kb = 0; kb < 4; ++kb)
                    #pragma unroll
                    for (int r = 0; r < 4; ++r)
                        if (kb * 16 + lg * 4 + r > gwid * 16 + li) sA[kb][r] = -2e30f;
            }
            if (t == 2 * st + 1) {               // last tile: A fully masked, B diagonal
                #pragma unroll
                for (int kb = 0; kb < 4; ++kb)
                    #pragma unroll
                    for (int r = 0; r < 4; ++r) {
                        sA[kb][r] = -2e30f;
                        if (kb * 16 + lg * 4 + r > gwid * 16 + li) sB[kb][r] = -2e30f;
                    }
            }

            { // softmax set A (defer-rescale, exact; base-2 domain)
                float mt = fmaxf(fmaxf(fmaxf(sA[0][0], sA[0][1]), fmaxf(sA[0][2], sA[0][3])),
                                 fmaxf(fmaxf(sA[1][0], sA[1][1]), fmaxf(sA[1][2], sA[1][3])));
                mt = fmaxf(mt, fmaxf(fmaxf(fmaxf(sA[2][0], sA[2][1]), fmaxf(sA[2][2], sA[2][3])),
                                     fmaxf(fmaxf(sA[3][0], sA[3][1]), fmaxf(sA[3][2], sA[3][3]))));
                mt = fmaxf(mt, __shfl_xor(mt, 16));
                mt = fmaxf(mt, __shfl_xor(mt, 32));
                if (!__all(mt <= mA)) {
                    const float mn = fmaxf(mA, mt);
                    const float sc = fexp2(mA - mn);
                    mA = mn;
                    lA *= sc;
                    #pragma unroll
                    for (int db = 0; db < 8; ++db) oA[db] *= sc;
                }
                float rs = 0.f;
                #pragma unroll
                for (int kb = 0; kb < 4; ++kb)
                    #pragma unroll
                    for (int r = 0; r < 4; ++r) {
                        float p = fexp2(sA[kb][r] - mA);
                        sA[kb][r] = p; rs += p;
                    }
                rs += __shfl_xor(rs, 16);
                rs += __shfl_xor(rs, 32);
                lA += rs;
                #pragma unroll
                for (int kb = 0; kb < 4; ++kb) {
                    const int g = kb * 2 + (lg >> 1);
                    const int sw = ((g ^ (li & 7)) << 3) + ((lg & 1) * 4);
                    uint2v w = {pk2(sA[kb][0], sA[kb][1]), pk2(sA[kb][2], sA[kb][3])};
                    *(uint2v*)&Ps[wid * 2048 + li * 64 + sw] = w;
                }
            }
            { // softmax set B (defer-rescale, exact; base-2 domain)
                float mt = fmaxf(fmaxf(fmaxf(sB[0][0], sB[0][1]), fmaxf(sB[0][2], sB[0][3])),
                                 fmaxf(fmaxf(sB[1][0], sB[1][1]), fmaxf(sB[1][2], sB[1][3])));
                mt = fmaxf(mt, fmaxf(fmaxf(fmaxf(sB[2][0], sB[2][1]), fmaxf(sB[2][2], sB[2][3])),
                                     fmaxf(fmaxf(sB[3][0], sB[3][1]), fmaxf(sB[3][2], sB[3][3]))));
                mt = fmaxf(mt, __shfl_xor(mt, 16));
                mt = fmaxf(mt, __shfl_xor(mt, 32));
                if (!__all(mt <= mB)) {
                    const float mn = fmaxf(mB, mt);
                    const float sc = fexp2(mB - mn);
                    mB = mn;
                    lB *= sc;
                    #pragma unroll
                    for (int db = 0; db < 8; ++db) oB[db] *= sc;
                }
                float rs = 0.f;
                #pragma unroll
                for (int kb = 0; kb < 4; ++kb)
                    #pragma unroll
                    for (int r = 0; r < 4; ++r) {
                        float p = fexp2(sB[kb][r] - mB);
                        sB[kb][r] = p; rs += p;
                    }
                rs += __shfl_xor(rs, 16);
                rs += __shfl_xor(rs, 32);
                lB += rs;
                #pragma unroll
                for (int kb = 0; kb < 4; ++kb) {
                    const int g = kb * 2 + (lg >> 1);
                    const int sw = ((g ^ (li & 7)) << 3) + ((lg & 1) * 4);
                    uint2v w = {pk2(sB[kb][0], sB[kb][1]), pk2(sB[kb][2], sB[kb][3])};
                    *(uint2v*)&Ps[wid * 2048 + 1024 + li * 64 + sw] = w;
                }
            }

            __builtin_amdgcn_s_setprio(1);
            #pragma unroll
            for (int kc = 0; kc < 2; ++kc) {
                short8 pA = *(const short8*)&Ps[wid * 2048 + li * 64 +
                                                (((kc * 4 + lg) ^ (li & 7)) << 3)];
                short8 pB = *(const short8*)&Ps[wid * 2048 + 1024 + li * 64 +
                                                (((kc * 4 + lg) ^ (li & 7)) << 3)];
                #pragma unroll
                for (int db = 0; db < 8; ++db) {
                    short8 vt = *(const short8*)&Vcur[(db * 16 + li) * 64 +
                                                      (((kc * 4 + lg) ^ (li & 7)) << 3)];
                    oA[db] = mfma_bf16(vt, pA, oA[db]);
                    oB[db] = mfma_bf16(vt, pB, oB[db]);
                }
            }
            __builtin_amdgcn_s_setprio(0);
        }

        // ---- cross-group merge + store (per set; fbuf [4][64][36] floats) ----
        float* fbuf = (float*)lds;
        ushort* Pw = lds + wid * 2176;           // wid 0..3 only (grp 0)
        __syncthreads();

        // ===== SET A =====
        if (grp == 1) {
            float* dst = fbuf + (gwid * 64 + lane) * 36;
            #pragma unroll
            for (int db = 0; db < 8; ++db) *(floatx4*)&dst[db * 4] = oA[db];
            dst[32] = mA; dst[33] = lA;
        }
        __syncthreads();
        if (grp == 0) {
            const float* src = fbuf + (gwid * 64 + lane) * 36;
            const float m1 = src[32], l1 = src[33];
            const float mm = fmaxf(mA, m1);
            const float s0 = fexp2(mA - mm), s1 = fexp2(m1 - mm);
            #pragma unroll
            for (int db = 0; db < 8; ++db) {
                floatx4 o1 = *(const floatx4*)&src[db * 4];
                oA[db] = oA[db] * s0 + o1 * s1;
            }
            lA = lA * s0 + l1 * s1;
        }
        __syncthreads();
        if (grp == 0) {
            const float inv = 1.0f / lA;
            #pragma unroll
            for (int db = 0; db < 8; ++db) {
                *(unsigned*)&Pw[li * 136 + db * 16 + lg * 4]     = pk2(oA[db][0] * inv, oA[db][1] * inv);
                *(unsigned*)&Pw[li * 136 + db * 16 + lg * 4 + 2] = pk2(oA[db][2] * inv, oA[db][3] * inv);
            }
            #pragma unroll
            for (int i = 0; i < 4; ++i) {
                const int q = lane >> 2, d8 = (lane & 3) + i * 4;
                short8 vv = *(const short8*)&Pw[q * 136 + d8 * 8];
                *(short8*)&out[(bS + qA + q) * E + h * Dh + d8 * 8] = vv;
            }
        }
        __syncthreads();

        // ===== SET B =====
        if (grp == 1) {
            float* dst = fbuf + (gwid * 64 + lane) * 36;
            #pragma unroll
            for (int db = 0; db < 8; ++db) *(floatx4*)&dst[db * 4] = oB[db];
            dst[32] = mB; dst[33] = lB;
        }
        __syncthreads();
        if (grp == 0) {
            const float* src = fbuf + (gwid * 64 + lane) * 36;
            const float m1 = src[32], l1 = src[33];
            const float mm = fmaxf(mB, m1);
            const float s0 = fexp2(mB - mm), s1 = fexp2(m1 - mm);
            #pragma unroll
            for (int db = 0; db < 8; ++db) {
                floatx4 o1 = *(const floatx4*)&src[db * 4];
                oB[db] = oB[db] * s0 + o1 * s1;
            }
            lB = lB * s0 + l1 * s1;
        }
        __syncthreads();
        if (grp == 0) {
            const float inv = 1.0f / lB;
            #pragma unroll
            for (int db = 0; db < 8; ++db) {
                *(unsigned*)&Pw[li * 136 + db * 16 + lg * 4]     = pk2(oB[db][0] * inv, oB[db][1] * inv);
                *(unsigned*)&Pw[li * 136 + db * 16 + lg * 4 + 2] = pk2(oB[db][2] * inv, oB[db][3] * inv);
            }
            #pragma unroll
            for (int i = 0; i < 4; ++i) {
                const int q = lane >> 2, d8 = (lane & 3) + i * 4;
                short8 vv = *(const short8*)&Pw[q * 136 + d8 * 8];
                *(short8*)&out[(bS + qB + q) * E + h * Dh + d8 * 8] = vv;
            }
        }
        __syncthreads();
    }
}

extern "C" void kernel_launch(void* const* d_in, const int* in_sizes, int n_in,
                              void* d_out, int out_size, void* d_ws, size_t ws_size,
                              hipStream_t stream) {
    (void)in_sizes; (void)n_in; (void)out_size; (void)ws_size;
    const float* hidden   = (const float*)d_in[0];
    const float* c_attn_w = (const float*)d_in[2];
    const float* c_attn_b = (const float*)d_in[3];
    const float* c_proj_w = (const float*)d_in[4];
    const float* c_proj_b = (const float*)d_in[5];
    float* outp = (float*)d_out;

    char* ws = (char*)d_ws;
    ushort* hbf  = (ushort*)ws;                                    // 4096x2048 bf16 -> later attn buf
    ushort* W1T  = (ushort*)(ws + (size_t)16777216);               // 2304x2048 bf16
    ushort* W2T  = (ushort*)(ws + (size_t)16777216 + 9437184);     // 2048x2048 bf16
    ushort* qkv  = (ushort*)(ws + (size_t)16777216 + 9437184 + 8388608);  // 4096x2304 bf16
    ushort* VTg  = (ushort*)(ws + (size_t)16777216 + 9437184 + 8388608 + 18874368); // 2x128x2048
    ushort* attn = hbf;   // reuse: hidden_bf16 dead after GEMM1

    prep_all<<<10368, 256, 0, stream>>>(hidden, hbf, c_attn_w, W1T, c_proj_w, W2T);

    gemm_db<0><<<dim3(18, 32), 256, 0, stream>>>(hbf, W1T, c_attn_b, qkv, 4096, 2304, 2048);
    v_transpose<<<dim3(32, 2, 2), 256, 0, stream>>>(qkv, VTg);
    attn_kernel<<<dim3(8, 16, 2), 512, 0, stream>>>(qkv, VTg, attn);
    gemm_db<1><<<dim3(16, 32), 256, 0, stream>>>(attn, W2T, c_proj_b, outp, 4096, 2048, 2048);
}